// Round 8
// baseline (331.521 us; speedup 1.0000x reference)
//
#include <hip/hip_runtime.h>
#include <hip/hip_bf16.h>

typedef unsigned short u16;
typedef __attribute__((ext_vector_type(8))) _Float16 half8;
typedef __attribute__((ext_vector_type(4))) float f32x4;

__device__ __forceinline__ u16 f2h(float f) {
  _Float16 h = (_Float16)f;
  union { _Float16 h; u16 u; } a; a.h = h;
  return a.u;
}

__device__ __forceinline__ float h2f(u16 u) {
  union { _Float16 h; u16 u; } a; a.u = u;
  return (float)a.h;
}

__device__ __forceinline__ float silu_f(float y) {
  return y / (1.0f + __expf(-y));
}

// async global->LDS, 16B per lane; LDS dest = wave-uniform base + lane*16
__device__ __forceinline__ void glds16(const u16* g, u16* l) {
  __builtin_amdgcn_global_load_lds(
      (__attribute__((address_space(1))) unsigned*)(g),
      (__attribute__((address_space(3))) unsigned*)(l), 16, 0, 0);
}

enum { EPI_BNSILU_N = 0, EPI_QKEV, EPI_RAW_F16, EPI_BNSILU_RES_M };

// C[m,n] = sum_k A[m,k]*B[n,k]  (NT GEMM, K-contiguous operands)
// 128x128 tile, BK=128 (four [128][32] slabs per operand; linear
// global_load_lds dest), 4 waves, 4x4 16x16x32 fp16 MFMA.
// DUAL: A k<256 from A (batched); k>=256 from A2 (batch-shared, lda 256).
// 1-D grid 32*TILES, XCD-affinity decode (id&7 pins batch group to XCD).
//
// History: R8 counted-vmcnt dbuf NULL; R9 (256,4) NULL (HW pins ~2 blocks);
// R10 BK 32->64 -8%; R11 dbuf-1-barrier NULL; R12 softmax-fold -7% (rev);
// R13 BK=128 -2% (best, kept). Barrier-rate axis now flat (LDS cap).
// R14 (this round): GEMMs untouched; vectorize transpose_x + softmax_rows.
template<int EPI, bool DUAL, int TILES, int GX>
__global__ __launch_bounds__(256, 2)
void gemm_nt(const u16* __restrict__ A, long long a_bs, int lda,
             const u16* __restrict__ A2,
             const u16* __restrict__ B, long long b_bs, int ldb,
             void* __restrict__ C0, long long c_bs, int ldc,
             void* __restrict__ C1, void* __restrict__ C2,
             int K,
             const float* __restrict__ p0, const float* __restrict__ p1,
             const float* __restrict__ res, long long res_bs)
{
  // A slabs [4][128][32] | B slabs [4][128][32]  (16384 u16 each)
  __shared__ u16 smem[32768];

  const int id = blockIdx.x;
  const int bz = (id & 7) + 8 * (id / (8 * TILES));
  const int tt = (id >> 3) % TILES;
  const int bm = tt % GX;
  const int bn = tt / GX;
  const u16* Ab = A + (long long)bz * a_bs;
  const u16* Bb = B + (long long)bz * b_bs;
  const int m0 = bm * 128;
  const int n0 = bn * 128;
  const int t = threadIdx.x;
  const int lane = t & 63;
  const int w = t >> 6;
  const int wm = (w & 1) * 64;
  const int wn = (w >> 1) * 64;
  const int q = lane >> 4;
  const int lr = lane & 15;

  f32x4 acc[4][4];
#pragma unroll
  for (int i = 0; i < 4; ++i)
#pragma unroll
    for (int j = 0; j < 4; ++j)
      acc[i][j] = (f32x4){0.f, 0.f, 0.f, 0.f};

  const int lrow = lane >> 2;
  const int kch = (lane & 3) ^ ((lane >> 2) & 3) ^ ((lane >> 4) & 3);
  const int lk = kch * 8;
  const u16* aR0 = Ab + (long long)(m0 + 32 * w + lrow) * lda + lk;
  const u16* aR1 = aR0 + 16LL * lda;
  const u16* bR0 = Bb + (long long)(n0 + 32 * w + lrow) * ldb + lk;
  const u16* bR1 = bR0 + 16LL * ldb;
  const u16* a2R0 = nullptr; const u16* a2R1 = nullptr;
  if constexpr (DUAL) {
    a2R0 = A2 + (long long)(m0 + 32 * w + lrow) * 256 + lk;
    a2R1 = a2R0 + 16LL * 256;
  }
  // per-wave staging slots (slab s at +4096*s)
  u16* la0 = smem + w * 1024;         u16* la1 = la0 + 512;
  u16* lb0 = smem + 16384 + w * 1024; u16* lb1 = lb0 + 512;
  const int fpos = (q ^ (lr & 3) ^ ((lr >> 2) & 3)) * 8;

  for (int k0 = 0; k0 < K; k0 += 128) {
    __syncthreads();
    if (!DUAL || k0 < 256) {
#pragma unroll
      for (int s = 0; s < 4; ++s) {
        const int ko = k0 + 32 * s;
        glds16(aR0 + ko, la0 + s * 4096);
        glds16(aR1 + ko, la1 + s * 4096);
      }
    } else {
#pragma unroll
      for (int s = 0; s < 4; ++s) {
        const int ko = k0 - 256 + 32 * s;
        glds16(a2R0 + ko, la0 + s * 4096);
        glds16(a2R1 + ko, la1 + s * 4096);
      }
    }
#pragma unroll
    for (int s = 0; s < 4; ++s) {
      const int ko = k0 + 32 * s;
      glds16(bR0 + ko, lb0 + s * 4096);
      glds16(bR1 + ko, lb1 + s * 4096);
    }
    __syncthreads();
#pragma unroll
    for (int h = 0; h < 4; ++h) {
      half8 af[4], bfr[4];
#pragma unroll
      for (int i = 0; i < 4; ++i)
        af[i] = *(const half8*)&smem[h * 4096 + (wm + i * 16 + lr) * 32 + fpos];
#pragma unroll
      for (int j = 0; j < 4; ++j)
        bfr[j] = *(const half8*)&smem[16384 + h * 4096 + (wn + j * 16 + lr) * 32 + fpos];
#pragma unroll
      for (int i = 0; i < 4; ++i)
#pragma unroll
        for (int j = 0; j < 4; ++j)
          acc[i][j] = __builtin_amdgcn_mfma_f32_16x16x32_f16(af[i], bfr[j], acc[i][j], 0, 0, 0);
    }
  }

  // ---- epilogues (C/D layout: col=lane&15, row=quad*4+reg) ----
  if constexpr (EPI == EPI_BNSILU_N) {
    u16* Cg = (u16*)C0 + (long long)bz * c_bs;
#pragma unroll
    for (int i = 0; i < 4; ++i)
#pragma unroll
      for (int j = 0; j < 4; ++j)
#pragma unroll
        for (int r = 0; r < 4; ++r) {
          const int m = m0 + wm + i * 16 + q * 4 + r;
          const int n = n0 + wn + j * 16 + lr;
          float v = acc[i][j][r];
          v = silu_f(v * (p0[n] * 0.99999500003749969f) + p1[n]);
          Cg[(long long)m * ldc + n] = f2h(v);
        }
  } else if constexpr (EPI == EPI_RAW_F16) {
    u16* Cg = (u16*)C0 + (long long)bz * c_bs;
#pragma unroll
    for (int i = 0; i < 4; ++i)
#pragma unroll
      for (int j = 0; j < 4; ++j)
#pragma unroll
        for (int r = 0; r < 4; ++r) {
          const int m = m0 + wm + i * 16 + q * 4 + r;
          const int n = n0 + wn + j * 16 + lr;
          Cg[(long long)m * ldc + n] = f2h(acc[i][j][r]);
        }
  } else if constexpr (EPI == EPI_BNSILU_RES_M) {
    float* Cg = (float*)C0 + (long long)bz * c_bs;
    const float* rg = res + (long long)bz * res_bs;
#pragma unroll
    for (int i = 0; i < 4; ++i)
#pragma unroll
      for (int j = 0; j < 4; ++j)
#pragma unroll
        for (int r = 0; r < 4; ++r) {
          const int m = m0 + wm + i * 16 + q * 4 + r;
          const int n = n0 + wn + j * 16 + lr;
          float v = acc[i][j][r];
          v = silu_f(v * (p0[m] * 0.99999500003749969f) + p1[m]);
          const long long idx = (long long)m * ldc + n;
          Cg[idx] = v + rg[idx];
        }
  } else {
    // EPI_QKEV: n-segment 0=q 1=k 2=e 3=v(transposed)
    const int seg = n0 >> 8;
    const int nb = n0 & 255;  // 0 or 128
    if (seg < 3) {
      u16* dst; long long bs; int ld2;
      if (seg == 0) { dst = (u16*)C0; bs = 262144; ld2 = 256; }
      else { dst = (u16*)C1 + (seg == 2 ? 256 : 0); bs = 524288; ld2 = 512; }
      dst += (long long)bz * bs;
#pragma unroll
      for (int i = 0; i < 4; ++i)
#pragma unroll
        for (int j = 0; j < 4; ++j)
#pragma unroll
          for (int r = 0; r < 4; ++r) {
            const int m = m0 + wm + i * 16 + q * 4 + r;
            const int col = wn + j * 16 + lr;
            float v = acc[i][j][r] + p0[n0 + col];
            dst[(long long)m * ld2 + nb + col] = f2h(v);
          }
    } else {
      // v[c, j] = Y[j, 768+c] + bv[c]: transpose via LDS, 32-row slabs, stride 132
      u16* dst = (u16*)C2 + (long long)bz * 262144;
#pragma unroll
      for (int s = 0; s < 4; ++s) {
        const int rbase = s * 32;
        __syncthreads();
        if (wm == (rbase & 64)) {
          const int ibase = (rbase & 32) >> 4;
#pragma unroll
          for (int ii = 0; ii < 2; ++ii) {
            const int i = ibase + ii;
#pragma unroll
            for (int j = 0; j < 4; ++j)
#pragma unroll
              for (int r = 0; r < 4; ++r) {
                const int row32 = i * 16 + q * 4 + r - (rbase & 32);
                const int col = wn + j * 16 + lr;
                float v = acc[i][j][r] + p0[768 + nb + col];
                smem[row32 * 132 + col] = f2h(v);
              }
          }
        }
        __syncthreads();
#pragma unroll
        for (int p = 0; p < 2; ++p) {
          const int lin = p * 256 + t;
          const int c = lin >> 2;
          const int mc = lin & 3;
          u16 tmp[8];
#pragma unroll
          for (int r8 = 0; r8 < 8; ++r8)
            tmp[r8] = smem[(mc * 8 + r8) * 132 + c];
          *(half8*)&dst[(long long)(nb + c) * 1024 + m0 + rbase + mc * 8] =
              *(const half8*)tmp;
        }
      }
    }
  }
}

// x [B,512,1024] fp32 -> xT [B,1024,512] fp16; 64x64 tiles,
// float4 global reads (256B/16-lane segments), half8 (16B) stores.
__global__ __launch_bounds__(256)
void transpose_x(const float* __restrict__ x, u16* __restrict__ xT) {
  __shared__ float tile[64][65];
  const int b = blockIdx.z;
  const int n0 = blockIdx.x * 64;
  const int d0 = blockIdx.y * 64;
  const int t = threadIdx.x;
  const float* src = x + (long long)b * 524288;
  const int rr = t >> 4;   // 0..15
  const int cc = t & 15;   // float4 column
#pragma unroll
  for (int i = 0; i < 4; ++i) {
    const int r = rr + i * 16;
    const float4 v = *(const float4*)&src[(long long)(d0 + r) * 1024 + n0 + cc * 4];
    tile[r][cc * 4 + 0] = v.x;
    tile[r][cc * 4 + 1] = v.y;
    tile[r][cc * 4 + 2] = v.z;
    tile[r][cc * 4 + 3] = v.w;
  }
  __syncthreads();
  u16* dst = xT + (long long)b * 524288;
  const int d8 = t & 7;    // 8-wide d slot
  const int nn = t >> 3;   // 0..31
#pragma unroll
  for (int i = 0; i < 2; ++i) {
    const int n = nn + i * 32;
    u16 tmp[8];
#pragma unroll
    for (int e = 0; e < 8; ++e) tmp[e] = f2h(tile[d8 * 8 + e][n]);
    *(half8*)&dst[(long long)(n0 + n) * 512 + d0 + d8 * 8] = *(const half8*)tmp;
  }
}

// weights: w1 | stacked(wq,wk,we,wv) | w2 -> fp16; fused bias (fp32) qkev
__global__ __launch_bounds__(256)
void convert_w(const float* __restrict__ w1, const float* __restrict__ wq,
               const float* __restrict__ wk, const float* __restrict__ wv,
               const float* __restrict__ we, const float* __restrict__ w2,
               const float* __restrict__ bq, const float* __restrict__ bk,
               const float* __restrict__ be, const float* __restrict__ bv,
               u16* __restrict__ dstw, float* __restrict__ bbuf) {
  int id = blockIdx.x * 256 + threadIdx.x;
  if (id < 524288) {
    float v;
    if (id < 131072) v = w1[id];
    else if (id < 393216) {
      int s = id - 131072, o = s >> 8, c = s & 255;
      if (o < 256) v = wq[o * 256 + c];
      else if (o < 512) v = wk[(o - 256) * 256 + c];
      else if (o < 768) v = we[(o - 512) * 256 + c];
      else v = wv[(o - 768) * 256 + c];
    } else v = w2[id - 393216];
    dstw[id] = f2h(v);
  } else {
    int i = id - 524288;
    float v;
    if (i < 256) v = bq[i];
    else if (i < 512) v = bk[i - 256];
    else if (i < 768) v = be[i - 512];
    else v = bv[i - 768];
    bbuf[i] = v;
  }
}

// posT[n,c] = fp16(rel_h[c, n>>5] + rel_w[c, n&31])
__global__ __launch_bounds__(256)
void pos_compute(const float* __restrict__ rh, const float* __restrict__ rw,
                 u16* __restrict__ posT) {
  const int n = blockIdx.x;
  const int c = threadIdx.x;
  posT[n * 256 + c] = f2h(rh[c * 32 + (n >> 5)] + rw[c * 32 + (n & 31)]);
}

// in-place softmax on fp16 rows of 1024; 2 rows/block, 16B/lane
__global__ __launch_bounds__(256)
void softmax_rows(u16* __restrict__ logits) {
  __shared__ float redm[2][2], reds[2][2];
  const int t = threadIdx.x;
  const int row = t >> 7;          // 0/1
  const int l = t & 127;           // lane within row
  const int wv = (t >> 6) & 1;     // wave within row
  u16* p = logits + (long long)blockIdx.x * 2048 + row * 1024;
  half8 raw = ((const half8*)p)[l];
  float v[8];
#pragma unroll
  for (int e = 0; e < 8; ++e) v[e] = (float)raw[e];
  float mx = v[0];
#pragma unroll
  for (int e = 1; e < 8; ++e) mx = fmaxf(mx, v[e]);
#pragma unroll
  for (int off = 32; off > 0; off >>= 1) mx = fmaxf(mx, __shfl_down(mx, off));
  if ((t & 63) == 0) redm[row][wv] = mx;
  __syncthreads();
  mx = fmaxf(redm[row][0], redm[row][1]);
  float ev[8];
  float s = 0.f;
#pragma unroll
  for (int e = 0; e < 8; ++e) { ev[e] = __expf(v[e] - mx); s += ev[e]; }
#pragma unroll
  for (int off = 32; off > 0; off >>= 1) s += __shfl_down(s, off);
  if ((t & 63) == 0) reds[row][wv] = s;
  __syncthreads();
  const float inv = 1.0f / (reds[row][0] + reds[row][1]);
  half8 o;
#pragma unroll
  for (int e = 0; e < 8; ++e) o[e] = (_Float16)(ev[e] * inv);
  ((half8*)p)[l] = o;
}

extern "C" void kernel_launch(void* const* d_in, const int* in_sizes, int n_in,
                              void* d_out, int out_size, void* d_ws, size_t ws_size,
                              hipStream_t stream) {
  const float* x  = (const float*)d_in[0];
  const float* w1 = (const float*)d_in[1];
  const float* g1 = (const float*)d_in[2];
  const float* b1 = (const float*)d_in[3];
  const float* wq = (const float*)d_in[4];
  const float* bq = (const float*)d_in[5];
  const float* wk = (const float*)d_in[6];
  const float* bk = (const float*)d_in[7];
  const float* wv = (const float*)d_in[8];
  const float* bv = (const float*)d_in[9];
  const float* we = (const float*)d_in[10];
  const float* be = (const float*)d_in[11];
  const float* rh = (const float*)d_in[12];
  const float* rw = (const float*)d_in[13];
  const float* w2 = (const float*)d_in[14];
  const float* g2 = (const float*)d_in[15];
  const float* b2 = (const float*)d_in[16];
  float* out = (float*)d_out;
  char* ws = (char*)d_ws;

  // ---- workspace (256 MiB available) ----
  u16* xT     = (u16*)(ws + 0);           // [B,1024,512] f16   32 MiB
  u16* x1t    = (u16*)(ws + 33554432);    // [B,1024,256] f16   16 MiB
  u16* qbuf   = (u16*)(ws + 50331648);    // [B,1024,256] f16   16 MiB
  u16* kcat   = (u16*)(ws + 67108864);    // [B,1024,512] f16   32 MiB (k|e)
  u16* vbuf   = (u16*)(ws + 100663296);   // [B,256,1024] f16   16 MiB
  u16* outt   = (u16*)(ws + 117440512);   // [B,1024,256] f16   16 MiB
  u16* posT   = (u16*)(ws + 134217728);   // [1024,256]   f16  512 KiB
  u16* wbuf   = (u16*)(ws + 134742016);   // packed weights      1 MiB
  float* bbuf = (float*)(ws + 135790592); // fused qkev bias     4 KiB
  u16* logits = (u16*)(ws + 142606336);   // [B,1024,1024] f16  64 MiB

  u16* w1b    = wbuf;            // [256,512]
  u16* wqkve  = wbuf + 131072;   // [1024,256] stacked q|k|e|v
  u16* w2b    = wbuf + 393216;   // [512,256]

  transpose_x<<<dim3(16, 8, 32), 256, 0, stream>>>(x, xT);
  convert_w<<<dim3(2052), 256, 0, stream>>>(w1, wq, wk, wv, we, w2,
                                            bq, bk, be, bv, wbuf, bbuf);
  pos_compute<<<dim3(1024), 256, 0, stream>>>(rh, rw, posT);

  // cv1: x1t[n,c] = silu(bn(xT[n,:] . w1[c,:]))   M=1024 N=256 K=512
  gemm_nt<EPI_BNSILU_N, false, 16, 8><<<dim3(512), 256, 0, stream>>>(
      xT, 524288LL, 512, nullptr, w1b, 0LL, 512,
      x1t, 262144LL, 256, nullptr, nullptr, 512, g1, b1, nullptr, 0LL);

  // fused qkev: Y[n,o] = x1t[n,:] . wqkve[o,:] + b[o]   M=1024 N=1024 K=256
  gemm_nt<EPI_QKEV, false, 64, 8><<<dim3(2048), 256, 0, stream>>>(
      x1t, 262144LL, 256, nullptr, wqkve, 0LL, 256,
      qbuf, 262144LL, 256, kcat, vbuf, 256, bbuf, nullptr, nullptr, 0LL);

  // logits[i,j] = [q(b)|posT][i,:] . kcat[j,:]   M=1024 N=1024 K=512 (dual A)
  gemm_nt<EPI_RAW_F16, true, 64, 8><<<dim3(2048), 256, 0, stream>>>(
      qbuf, 262144LL, 256, posT, kcat, 524288LL, 512,
      logits, 1048576LL, 1024, nullptr, nullptr, 512, nullptr, nullptr, nullptr, 0LL);

  // softmax in place over all 32K rows (2 rows per block)
  softmax_rows<<<dim3(16384), 256, 0, stream>>>(logits);

  // outt[i,c] = attn[i,:] . vbuf[c,:]   M=1024 N=256 K=1024
  gemm_nt<EPI_RAW_F16, false, 16, 8><<<dim3(512), 256, 0, stream>>>(
      logits, 1048576LL, 1024, nullptr, vbuf, 262144LL, 1024,
      outt, 262144LL, 256, nullptr, nullptr, 1024, nullptr, nullptr, nullptr, 0LL);

  // cv2 + residual: out = x + silu(bn(w2 . outt))   M=512 N=1024 K=256
  gemm_nt<EPI_BNSILU_RES_M, false, 32, 4><<<dim3(1024), 256, 0, stream>>>(
      w2b, 0LL, 256, nullptr, outt, 262144LL, 256,
      out, 524288LL, 1024, nullptr, nullptr, 256, g2, b2, x, 524288LL);
}

// Round 9
// 327.076 us; speedup vs baseline: 1.0136x; 1.0136x over previous
//
#include <hip/hip_runtime.h>
#include <hip/hip_bf16.h>

typedef unsigned short u16;
typedef __attribute__((ext_vector_type(8))) _Float16 half8;
typedef __attribute__((ext_vector_type(4))) float f32x4;

__device__ __forceinline__ u16 f2h(float f) {
  _Float16 h = (_Float16)f;
  union { _Float16 h; u16 u; } a; a.h = h;
  return a.u;
}

__device__ __forceinline__ float h2f(u16 u) {
  union { _Float16 h; u16 u; } a; a.u = u;
  return (float)a.h;
}

__device__ __forceinline__ float silu_f(float y) {
  return y / (1.0f + __expf(-y));
}

// async global->LDS, 16B per lane; LDS dest = wave-uniform base + lane*16
__device__ __forceinline__ void glds16(const u16* g, u16* l) {
  __builtin_amdgcn_global_load_lds(
      (__attribute__((address_space(1))) unsigned*)(g),
      (__attribute__((address_space(3))) unsigned*)(l), 16, 0, 0);
}

enum { EPI_BNSILU_N = 0, EPI_QKEV, EPI_RAW_F16, EPI_BNSILU_RES_M };

// ======================= 128^2 kernel (unchanged, R7/R8 best) ==============
template<int EPI, bool DUAL, int TILES, int GX>
__global__ __launch_bounds__(256, 2)
void gemm_nt(const u16* __restrict__ A, long long a_bs, int lda,
             const u16* __restrict__ A2,
             const u16* __restrict__ B, long long b_bs, int ldb,
             void* __restrict__ C0, long long c_bs, int ldc,
             void* __restrict__ C1, void* __restrict__ C2,
             int K,
             const float* __restrict__ p0, const float* __restrict__ p1,
             const float* __restrict__ res, long long res_bs)
{
  // A slabs [4][128][32] | B slabs [4][128][32]  (16384 u16 each)
  __shared__ u16 smem[32768];

  const int id = blockIdx.x;
  const int bz = (id & 7) + 8 * (id / (8 * TILES));
  const int tt = (id >> 3) % TILES;
  const int bm = tt % GX;
  const int bn = tt / GX;
  const u16* Ab = A + (long long)bz * a_bs;
  const u16* Bb = B + (long long)bz * b_bs;
  const int m0 = bm * 128;
  const int n0 = bn * 128;
  const int t = threadIdx.x;
  const int lane = t & 63;
  const int w = t >> 6;
  const int wm = (w & 1) * 64;
  const int wn = (w >> 1) * 64;
  const int q = lane >> 4;
  const int lr = lane & 15;

  f32x4 acc[4][4];
#pragma unroll
  for (int i = 0; i < 4; ++i)
#pragma unroll
    for (int j = 0; j < 4; ++j)
      acc[i][j] = (f32x4){0.f, 0.f, 0.f, 0.f};

  const int lrow = lane >> 2;
  const int kch = (lane & 3) ^ ((lane >> 2) & 3) ^ ((lane >> 4) & 3);
  const int lk = kch * 8;
  const u16* aR0 = Ab + (long long)(m0 + 32 * w + lrow) * lda + lk;
  const u16* aR1 = aR0 + 16LL * lda;
  const u16* bR0 = Bb + (long long)(n0 + 32 * w + lrow) * ldb + lk;
  const u16* bR1 = bR0 + 16LL * ldb;
  const u16* a2R0 = nullptr; const u16* a2R1 = nullptr;
  if constexpr (DUAL) {
    a2R0 = A2 + (long long)(m0 + 32 * w + lrow) * 256 + lk;
    a2R1 = a2R0 + 16LL * 256;
  }
  // per-wave staging slots (slab s at +4096*s)
  u16* la0 = smem + w * 1024;         u16* la1 = la0 + 512;
  u16* lb0 = smem + 16384 + w * 1024; u16* lb1 = lb0 + 512;
  const int fpos = (q ^ (lr & 3) ^ ((lr >> 2) & 3)) * 8;

  for (int k0 = 0; k0 < K; k0 += 128) {
    __syncthreads();
    if (!DUAL || k0 < 256) {
#pragma unroll
      for (int s = 0; s < 4; ++s) {
        const int ko = k0 + 32 * s;
        glds16(aR0 + ko, la0 + s * 4096);
        glds16(aR1 + ko, la1 + s * 4096);
      }
    } else {
#pragma unroll
      for (int s = 0; s < 4; ++s) {
        const int ko = k0 - 256 + 32 * s;
        glds16(a2R0 + ko, la0 + s * 4096);
        glds16(a2R1 + ko, la1 + s * 4096);
      }
    }
#pragma unroll
    for (int s = 0; s < 4; ++s) {
      const int ko = k0 + 32 * s;
      glds16(bR0 + ko, lb0 + s * 4096);
      glds16(bR1 + ko, lb1 + s * 4096);
    }
    __syncthreads();
#pragma unroll
    for (int h = 0; h < 4; ++h) {
      half8 af[4], bfr[4];
#pragma unroll
      for (int i = 0; i < 4; ++i)
        af[i] = *(const half8*)&smem[h * 4096 + (wm + i * 16 + lr) * 32 + fpos];
#pragma unroll
      for (int j = 0; j < 4; ++j)
        bfr[j] = *(const half8*)&smem[16384 + h * 4096 + (wn + j * 16 + lr) * 32 + fpos];
#pragma unroll
      for (int i = 0; i < 4; ++i)
#pragma unroll
        for (int j = 0; j < 4; ++j)
          acc[i][j] = __builtin_amdgcn_mfma_f32_16x16x32_f16(af[i], bfr[j], acc[i][j], 0, 0, 0);
    }
  }

  // ---- epilogues (C/D layout: col=lane&15, row=quad*4+reg) ----
  if constexpr (EPI == EPI_BNSILU_N) {
    u16* Cg = (u16*)C0 + (long long)bz * c_bs;
#pragma unroll
    for (int i = 0; i < 4; ++i)
#pragma unroll
      for (int j = 0; j < 4; ++j)
#pragma unroll
        for (int r = 0; r < 4; ++r) {
          const int m = m0 + wm + i * 16 + q * 4 + r;
          const int n = n0 + wn + j * 16 + lr;
          float v = acc[i][j][r];
          v = silu_f(v * (p0[n] * 0.99999500003749969f) + p1[n]);
          Cg[(long long)m * ldc + n] = f2h(v);
        }
  } else if constexpr (EPI == EPI_RAW_F16) {
    u16* Cg = (u16*)C0 + (long long)bz * c_bs;
#pragma unroll
    for (int i = 0; i < 4; ++i)
#pragma unroll
      for (int j = 0; j < 4; ++j)
#pragma unroll
        for (int r = 0; r < 4; ++r) {
          const int m = m0 + wm + i * 16 + q * 4 + r;
          const int n = n0 + wn + j * 16 + lr;
          Cg[(long long)m * ldc + n] = f2h(acc[i][j][r]);
        }
  } else if constexpr (EPI == EPI_BNSILU_RES_M) {
    float* Cg = (float*)C0 + (long long)bz * c_bs;
    const float* rg = res + (long long)bz * res_bs;
#pragma unroll
    for (int i = 0; i < 4; ++i)
#pragma unroll
      for (int j = 0; j < 4; ++j)
#pragma unroll
        for (int r = 0; r < 4; ++r) {
          const int m = m0 + wm + i * 16 + q * 4 + r;
          const int n = n0 + wn + j * 16 + lr;
          float v = acc[i][j][r];
          v = silu_f(v * (p0[m] * 0.99999500003749969f) + p1[m]);
          const long long idx = (long long)m * ldc + n;
          Cg[idx] = v + rg[idx];
        }
  } else {
    // EPI_QKEV: n-segment 0=q 1=k 2=e 3=v(transposed)
    const int seg = n0 >> 8;
    const int nb = n0 & 255;  // 0 or 128
    if (seg < 3) {
      u16* dst; long long bs; int ld2;
      if (seg == 0) { dst = (u16*)C0; bs = 262144; ld2 = 256; }
      else { dst = (u16*)C1 + (seg == 2 ? 256 : 0); bs = 524288; ld2 = 512; }
      dst += (long long)bz * bs;
#pragma unroll
      for (int i = 0; i < 4; ++i)
#pragma unroll
        for (int j = 0; j < 4; ++j)
#pragma unroll
          for (int r = 0; r < 4; ++r) {
            const int m = m0 + wm + i * 16 + q * 4 + r;
            const int col = wn + j * 16 + lr;
            float v = acc[i][j][r] + p0[n0 + col];
            dst[(long long)m * ld2 + nb + col] = f2h(v);
          }
    } else {
      // v[c, j] = Y[j, 768+c] + bv[c]: transpose via LDS, 32-row slabs, stride 132
      u16* dst = (u16*)C2 + (long long)bz * 262144;
#pragma unroll
      for (int s = 0; s < 4; ++s) {
        const int rbase = s * 32;
        __syncthreads();
        if (wm == (rbase & 64)) {
          const int ibase = (rbase & 32) >> 4;
#pragma unroll
          for (int ii = 0; ii < 2; ++ii) {
            const int i = ibase + ii;
#pragma unroll
            for (int j = 0; j < 4; ++j)
#pragma unroll
              for (int r = 0; r < 4; ++r) {
                const int row32 = i * 16 + q * 4 + r - (rbase & 32);
                const int col = wn + j * 16 + lr;
                float v = acc[i][j][r] + p0[768 + nb + col];
                smem[row32 * 132 + col] = f2h(v);
              }
          }
        }
        __syncthreads();
#pragma unroll
        for (int p = 0; p < 2; ++p) {
          const int lin = p * 256 + t;
          const int c = lin >> 2;
          const int mc = lin & 3;
          u16 tmp[8];
#pragma unroll
          for (int r8 = 0; r8 < 8; ++r8)
            tmp[r8] = smem[(mc * 8 + r8) * 132 + c];
          *(half8*)&dst[(long long)(nb + c) * 1024 + m0 + rbase + mc * 8] =
              *(const half8*)tmp;
        }
      }
    }
  }
}

// ======================= 256^2 kernel (new, logits only) ====================
// BM=BN=256, BK=64 (two 32-k slabs per operand), 8 waves (2M x 4N),
// per-wave output 128x64 (acc[8][4] f32x4 = 128 f32). Single-buffered LDS
// 64KB, 2 barriers per K-step (proven-safe schedule). Same slab/XOR staging
// as the 128^2 kernel, scaled. DUAL: k<256 from A, k>=256 from A2 (lda 256).
// Raw-f16 epilogue. Grid 8*TILES(=16) blocks-per-batch-group, 512 blocks.
// 1 block/CU (VGPR ~200 -> 2 waves/SIMD), 8 waves/CU.
template<bool DUAL>
__global__ __launch_bounds__(512, 2)
void gemm256_nt(const u16* __restrict__ A, long long a_bs, int lda,
                const u16* __restrict__ A2,
                const u16* __restrict__ B, long long b_bs, int ldb,
                u16* __restrict__ C0, long long c_bs, int ldc, int K)
{
  // A: 2 slabs [256][32] at 0, 8192 | B: 2 slabs at 16384, 24576 (u16 units)
  __shared__ u16 smem[32768];

  const int id = blockIdx.x;
  const int bz = (id & 7) + 8 * (id / (8 * 16));
  const int tt = (id >> 3) % 16;
  const int m0 = (tt & 3) * 256;
  const int n0 = (tt >> 2) * 256;
  const u16* Ab = A + (long long)bz * a_bs;
  const u16* Bb = B + (long long)bz * b_bs;
  const int t = threadIdx.x;
  const int lane = t & 63;
  const int w = t >> 6;           // 0..7
  const int wm = (w & 1) * 128;   // 2 waves in M
  const int wn = (w >> 1) * 64;   // 4 waves in N
  const int q = lane >> 4;
  const int lr = lane & 15;

  f32x4 acc[8][4];
#pragma unroll
  for (int i = 0; i < 8; ++i)
#pragma unroll
    for (int j = 0; j < 4; ++j)
      acc[i][j] = (f32x4){0.f, 0.f, 0.f, 0.f};

  const int lrow = lane >> 2;
  const int kch = (lane & 3) ^ ((lane >> 2) & 3) ^ ((lane >> 4) & 3);
  const int lk = kch * 8;
  // each wave stages rows 32w..32w+31 of the 256-row panel
  const u16* aR0 = Ab + (long long)(m0 + 32 * w + lrow) * lda + lk;
  const u16* aR1 = aR0 + 16LL * lda;
  const u16* bR0 = Bb + (long long)(n0 + 32 * w + lrow) * ldb + lk;
  const u16* bR1 = bR0 + 16LL * ldb;
  const u16* a2R0 = nullptr; const u16* a2R1 = nullptr;
  if constexpr (DUAL) {
    a2R0 = A2 + (long long)(m0 + 32 * w + lrow) * 256 + lk;
    a2R1 = a2R0 + 16LL * 256;
  }
  u16* la0 = smem + w * 1024;         u16* la1 = la0 + 512;
  u16* lb0 = smem + 16384 + w * 1024; u16* lb1 = lb0 + 512;
  const int fpos = (q ^ (lr & 3) ^ ((lr >> 2) & 3)) * 8;

  for (int k0 = 0; k0 < K; k0 += 64) {
    __syncthreads();
    if (!DUAL || k0 < 256) {
      glds16(aR0 + k0, la0);        glds16(aR1 + k0, la1);
      glds16(aR0 + k0 + 32, la0 + 8192); glds16(aR1 + k0 + 32, la1 + 8192);
    } else {
      glds16(a2R0 + (k0 - 256), la0);        glds16(a2R1 + (k0 - 256), la1);
      glds16(a2R0 + (k0 - 224), la0 + 8192); glds16(a2R1 + (k0 - 224), la1 + 8192);
    }
    glds16(bR0 + k0, lb0);        glds16(bR1 + k0, lb1);
    glds16(bR0 + k0 + 32, lb0 + 8192); glds16(bR1 + k0 + 32, lb1 + 8192);
    __syncthreads();
#pragma unroll
    for (int h = 0; h < 2; ++h) {
      half8 bfr[4];
#pragma unroll
      for (int j = 0; j < 4; ++j)
        bfr[j] = *(const half8*)&smem[16384 + h * 8192 + (wn + j * 16 + lr) * 32 + fpos];
#pragma unroll
      for (int i = 0; i < 8; ++i) {
        const half8 af = *(const half8*)&smem[h * 8192 + (wm + i * 16 + lr) * 32 + fpos];
#pragma unroll
        for (int j = 0; j < 4; ++j)
          acc[i][j] = __builtin_amdgcn_mfma_f32_16x16x32_f16(af, bfr[j], acc[i][j], 0, 0, 0);
      }
    }
  }

  u16* Cg = C0 + (long long)bz * c_bs;
#pragma unroll
  for (int i = 0; i < 8; ++i)
#pragma unroll
    for (int j = 0; j < 4; ++j)
#pragma unroll
      for (int r = 0; r < 4; ++r) {
        const int m = m0 + wm + i * 16 + q * 4 + r;
        const int n = n0 + wn + j * 16 + lr;
        Cg[(long long)m * ldc + n] = f2h(acc[i][j][r]);
      }
}

// x [B,512,1024] fp32 -> xT [B,1024,512] fp16; 64x64 tiles,
// float4 global reads (256B/16-lane segments), half8 (16B) stores.
__global__ __launch_bounds__(256)
void transpose_x(const float* __restrict__ x, u16* __restrict__ xT) {
  __shared__ float tile[64][65];
  const int b = blockIdx.z;
  const int n0 = blockIdx.x * 64;
  const int d0 = blockIdx.y * 64;
  const int t = threadIdx.x;
  const float* src = x + (long long)b * 524288;
  const int rr = t >> 4;   // 0..15
  const int cc = t & 15;   // float4 column
#pragma unroll
  for (int i = 0; i < 4; ++i) {
    const int r = rr + i * 16;
    const float4 v = *(const float4*)&src[(long long)(d0 + r) * 1024 + n0 + cc * 4];
    tile[r][cc * 4 + 0] = v.x;
    tile[r][cc * 4 + 1] = v.y;
    tile[r][cc * 4 + 2] = v.z;
    tile[r][cc * 4 + 3] = v.w;
  }
  __syncthreads();
  u16* dst = xT + (long long)b * 524288;
  const int d8 = t & 7;    // 8-wide d slot
  const int nn = t >> 3;   // 0..31
#pragma unroll
  for (int i = 0; i < 2; ++i) {
    const int n = nn + i * 32;
    u16 tmp[8];
#pragma unroll
    for (int e = 0; e < 8; ++e) tmp[e] = f2h(tile[d8 * 8 + e][n]);
    *(half8*)&dst[(long long)(n0 + n) * 512 + d0 + d8 * 8] = *(const half8*)tmp;
  }
}

// weights: w1 | stacked(wq,wk,we,wv) | w2 -> fp16; fused bias (fp32) qkev
__global__ __launch_bounds__(256)
void convert_w(const float* __restrict__ w1, const float* __restrict__ wq,
               const float* __restrict__ wk, const float* __restrict__ wv,
               const float* __restrict__ we, const float* __restrict__ w2,
               const float* __restrict__ bq, const float* __restrict__ bk,
               const float* __restrict__ be, const float* __restrict__ bv,
               u16* __restrict__ dstw, float* __restrict__ bbuf) {
  int id = blockIdx.x * 256 + threadIdx.x;
  if (id < 524288) {
    float v;
    if (id < 131072) v = w1[id];
    else if (id < 393216) {
      int s = id - 131072, o = s >> 8, c = s & 255;
      if (o < 256) v = wq[o * 256 + c];
      else if (o < 512) v = wk[(o - 256) * 256 + c];
      else if (o < 768) v = we[(o - 512) * 256 + c];
      else v = wv[(o - 768) * 256 + c];
    } else v = w2[id - 393216];
    dstw[id] = f2h(v);
  } else {
    int i = id - 524288;
    float v;
    if (i < 256) v = bq[i];
    else if (i < 512) v = bk[i - 256];
    else if (i < 768) v = be[i - 512];
    else v = bv[i - 768];
    bbuf[i] = v;
  }
}

// posT[n,c] = fp16(rel_h[c, n>>5] + rel_w[c, n&31])
__global__ __launch_bounds__(256)
void pos_compute(const float* __restrict__ rh, const float* __restrict__ rw,
                 u16* __restrict__ posT) {
  const int n = blockIdx.x;
  const int c = threadIdx.x;
  posT[n * 256 + c] = f2h(rh[c * 32 + (n >> 5)] + rw[c * 32 + (n & 31)]);
}

// in-place softmax on fp16 rows of 1024; 2 rows/block, 16B/lane
__global__ __launch_bounds__(256)
void softmax_rows(u16* __restrict__ logits) {
  __shared__ float redm[2][2], reds[2][2];
  const int t = threadIdx.x;
  const int row = t >> 7;          // 0/1
  const int l = t & 127;           // lane within row
  const int wv = (t >> 6) & 1;     // wave within row
  u16* p = logits + (long long)blockIdx.x * 2048 + row * 1024;
  half8 raw = ((const half8*)p)[l];
  float v[8];
#pragma unroll
  for (int e = 0; e < 8; ++e) v[e] = (float)raw[e];
  float mx = v[0];
#pragma unroll
  for (int e = 1; e < 8; ++e) mx = fmaxf(mx, v[e]);
#pragma unroll
  for (int off = 32; off > 0; off >>= 1) mx = fmaxf(mx, __shfl_down(mx, off));
  if ((t & 63) == 0) redm[row][wv] = mx;
  __syncthreads();
  mx = fmaxf(redm[row][0], redm[row][1]);
  float ev[8];
  float s = 0.f;
#pragma unroll
  for (int e = 0; e < 8; ++e) { ev[e] = __expf(v[e] - mx); s += ev[e]; }
#pragma unroll
  for (int off = 32; off > 0; off >>= 1) s += __shfl_down(s, off);
  if ((t & 63) == 0) reds[row][wv] = s;
  __syncthreads();
  const float inv = 1.0f / (reds[row][0] + reds[row][1]);
  half8 o;
#pragma unroll
  for (int e = 0; e < 8; ++e) o[e] = (_Float16)(ev[e] * inv);
  ((half8*)p)[l] = o;
}

extern "C" void kernel_launch(void* const* d_in, const int* in_sizes, int n_in,
                              void* d_out, int out_size, void* d_ws, size_t ws_size,
                              hipStream_t stream) {
  const float* x  = (const float*)d_in[0];
  const float* w1 = (const float*)d_in[1];
  const float* g1 = (const float*)d_in[2];
  const float* b1 = (const float*)d_in[3];
  const float* wq = (const float*)d_in[4];
  const float* bq = (const float*)d_in[5];
  const float* wk = (const float*)d_in[6];
  const float* bk = (const float*)d_in[7];
  const float* wv = (const float*)d_in[8];
  const float* bv = (const float*)d_in[9];
  const float* we = (const float*)d_in[10];
  const float* be = (const float*)d_in[11];
  const float* rh = (const float*)d_in[12];
  const float* rw = (const float*)d_in[13];
  const float* w2 = (const float*)d_in[14];
  const float* g2 = (const float*)d_in[15];
  const float* b2 = (const float*)d_in[16];
  float* out = (float*)d_out;
  char* ws = (char*)d_ws;

  // ---- workspace (256 MiB available) ----
  u16* xT     = (u16*)(ws + 0);           // [B,1024,512] f16   32 MiB
  u16* x1t    = (u16*)(ws + 33554432);    // [B,1024,256] f16   16 MiB
  u16* qbuf   = (u16*)(ws + 50331648);    // [B,1024,256] f16   16 MiB
  u16* kcat   = (u16*)(ws + 67108864);    // [B,1024,512] f16   32 MiB (k|e)
  u16* vbuf   = (u16*)(ws + 100663296);   // [B,256,1024] f16   16 MiB
  u16* outt   = (u16*)(ws + 117440512);   // [B,1024,256] f16   16 MiB
  u16* posT   = (u16*)(ws + 134217728);   // [1024,256]   f16  512 KiB
  u16* wbuf   = (u16*)(ws + 134742016);   // packed weights      1 MiB
  float* bbuf = (float*)(ws + 135790592); // fused qkev bias     4 KiB
  u16* logits = (u16*)(ws + 142606336);   // [B,1024,1024] f16  64 MiB

  u16* w1b    = wbuf;            // [256,512]
  u16* wqkve  = wbuf + 131072;   // [1024,256] stacked q|k|e|v
  u16* w2b    = wbuf + 393216;   // [512,256]

  transpose_x<<<dim3(16, 8, 32), 256, 0, stream>>>(x, xT);
  convert_w<<<dim3(2052), 256, 0, stream>>>(w1, wq, wk, wv, we, w2,
                                            bq, bk, be, bv, wbuf, bbuf);
  pos_compute<<<dim3(1024), 256, 0, stream>>>(rh, rw, posT);

  // cv1: x1t[n,c] = silu(bn(xT[n,:] . w1[c,:]))   M=1024 N=256 K=512
  gemm_nt<EPI_BNSILU_N, false, 16, 8><<<dim3(512), 256, 0, stream>>>(
      xT, 524288LL, 512, nullptr, w1b, 0LL, 512,
      x1t, 262144LL, 256, nullptr, nullptr, 512, g1, b1, nullptr, 0LL);

  // fused qkev: Y[n,o] = x1t[n,:] . wqkve[o,:] + b[o]   M=1024 N=1024 K=256
  gemm_nt<EPI_QKEV, false, 64, 8><<<dim3(2048), 256, 0, stream>>>(
      x1t, 262144LL, 256, nullptr, wqkve, 0LL, 256,
      qbuf, 262144LL, 256, kcat, vbuf, 256, bbuf, nullptr, nullptr, 0LL);

  // logits[i,j] = [q(b)|posT][i,:] . kcat[j,:]   M=1024 N=1024 K=512 (dual A)
  // 256^2 tile kernel: 16 tiles x 32 batches = 512 blocks, 512 threads
  gemm256_nt<true><<<dim3(512), 512, 0, stream>>>(
      qbuf, 262144LL, 256, posT, kcat, 524288LL, 512,
      logits, 1048576LL, 1024, 512);

  // softmax in place over all 32K rows (2 rows per block)
  softmax_rows<<<dim3(16384), 256, 0, stream>>>(logits);

  // outt[i,c] = attn[i,:] . vbuf[c,:]   M=1024 N=256 K=1024
  gemm_nt<EPI_RAW_F16, false, 16, 8><<<dim3(512), 256, 0, stream>>>(
      logits, 1048576LL, 1024, nullptr, vbuf, 262144LL, 1024,
      outt, 262144LL, 256, nullptr, nullptr, 1024, nullptr, nullptr, nullptr, 0LL);

  // cv2 + residual: out = x + silu(bn(w2 . outt))   M=512 N=1024 K=256
  gemm_nt<EPI_BNSILU_RES_M, false, 32, 4><<<dim3(1024), 256, 0, stream>>>(
      w2b, 0LL, 256, nullptr, outt, 262144LL, 256,
      out, 524288LL, 1024, nullptr, nullptr, 256, g2, b2, x, 524288LL);
}

// Round 11
// 319.892 us; speedup vs baseline: 1.0364x; 1.0225x over previous
//
#include <hip/hip_runtime.h>
#include <hip/hip_bf16.h>

typedef unsigned short u16;
typedef __attribute__((ext_vector_type(8))) _Float16 half8;
typedef __attribute__((ext_vector_type(4))) float f32x4;

__device__ __forceinline__ u16 f2h(float f) {
  _Float16 h = (_Float16)f;
  union { _Float16 h; u16 u; } a; a.h = h;
  return a.u;
}

__device__ __forceinline__ float h2f(u16 u) {
  union { _Float16 h; u16 u; } a; a.u = u;
  return (float)a.h;
}

__device__ __forceinline__ float silu_f(float y) {
  return y / (1.0f + __expf(-y));
}

// async global->LDS, 16B per lane; LDS dest = wave-uniform base + lane*16
__device__ __forceinline__ void glds16(const u16* g, u16* l) {
  __builtin_amdgcn_global_load_lds(
      (__attribute__((address_space(1))) unsigned*)(g),
      (__attribute__((address_space(3))) unsigned*)(l), 16, 0, 0);
}

enum { EPI_BNSILU_N = 0, EPI_QKEV, EPI_RAW_F16, EPI_BNSILU_RES_M };

// ======================= 128^2 kernel (unchanged, R7/R8 best) ==============
template<int EPI, bool DUAL, int TILES, int GX>
__global__ __launch_bounds__(256, 2)
void gemm_nt(const u16* __restrict__ A, long long a_bs, int lda,
             const u16* __restrict__ A2,
             const u16* __restrict__ B, long long b_bs, int ldb,
             void* __restrict__ C0, long long c_bs, int ldc,
             void* __restrict__ C1, void* __restrict__ C2,
             int K,
             const float* __restrict__ p0, const float* __restrict__ p1,
             const float* __restrict__ res, long long res_bs)
{
  // A slabs [4][128][32] | B slabs [4][128][32]  (16384 u16 each)
  __shared__ u16 smem[32768];

  const int id = blockIdx.x;
  const int bz = (id & 7) + 8 * (id / (8 * TILES));
  const int tt = (id >> 3) % TILES;
  const int bm = tt % GX;
  const int bn = tt / GX;
  const u16* Ab = A + (long long)bz * a_bs;
  const u16* Bb = B + (long long)bz * b_bs;
  const int m0 = bm * 128;
  const int n0 = bn * 128;
  const int t = threadIdx.x;
  const int lane = t & 63;
  const int w = t >> 6;
  const int wm = (w & 1) * 64;
  const int wn = (w >> 1) * 64;
  const int q = lane >> 4;
  const int lr = lane & 15;

  f32x4 acc[4][4];
#pragma unroll
  for (int i = 0; i < 4; ++i)
#pragma unroll
    for (int j = 0; j < 4; ++j)
      acc[i][j] = (f32x4){0.f, 0.f, 0.f, 0.f};

  const int lrow = lane >> 2;
  const int kch = (lane & 3) ^ ((lane >> 2) & 3) ^ ((lane >> 4) & 3);
  const int lk = kch * 8;
  const u16* aR0 = Ab + (long long)(m0 + 32 * w + lrow) * lda + lk;
  const u16* aR1 = aR0 + 16LL * lda;
  const u16* bR0 = Bb + (long long)(n0 + 32 * w + lrow) * ldb + lk;
  const u16* bR1 = bR0 + 16LL * ldb;
  const u16* a2R0 = nullptr; const u16* a2R1 = nullptr;
  if constexpr (DUAL) {
    a2R0 = A2 + (long long)(m0 + 32 * w + lrow) * 256 + lk;
    a2R1 = a2R0 + 16LL * 256;
  }
  // per-wave staging slots (slab s at +4096*s)
  u16* la0 = smem + w * 1024;         u16* la1 = la0 + 512;
  u16* lb0 = smem + 16384 + w * 1024; u16* lb1 = lb0 + 512;
  const int fpos = (q ^ (lr & 3) ^ ((lr >> 2) & 3)) * 8;

  for (int k0 = 0; k0 < K; k0 += 128) {
    __syncthreads();
    if (!DUAL || k0 < 256) {
#pragma unroll
      for (int s = 0; s < 4; ++s) {
        const int ko = k0 + 32 * s;
        glds16(aR0 + ko, la0 + s * 4096);
        glds16(aR1 + ko, la1 + s * 4096);
      }
    } else {
#pragma unroll
      for (int s = 0; s < 4; ++s) {
        const int ko = k0 - 256 + 32 * s;
        glds16(a2R0 + ko, la0 + s * 4096);
        glds16(a2R1 + ko, la1 + s * 4096);
      }
    }
#pragma unroll
    for (int s = 0; s < 4; ++s) {
      const int ko = k0 + 32 * s;
      glds16(bR0 + ko, lb0 + s * 4096);
      glds16(bR1 + ko, lb1 + s * 4096);
    }
    __syncthreads();
#pragma unroll
    for (int h = 0; h < 4; ++h) {
      half8 af[4], bfr[4];
#pragma unroll
      for (int i = 0; i < 4; ++i)
        af[i] = *(const half8*)&smem[h * 4096 + (wm + i * 16 + lr) * 32 + fpos];
#pragma unroll
      for (int j = 0; j < 4; ++j)
        bfr[j] = *(const half8*)&smem[16384 + h * 4096 + (wn + j * 16 + lr) * 32 + fpos];
#pragma unroll
      for (int i = 0; i < 4; ++i)
#pragma unroll
        for (int j = 0; j < 4; ++j)
          acc[i][j] = __builtin_amdgcn_mfma_f32_16x16x32_f16(af[i], bfr[j], acc[i][j], 0, 0, 0);
    }
  }

  // ---- epilogues (C/D layout: col=lane&15, row=quad*4+reg) ----
  if constexpr (EPI == EPI_BNSILU_N) {
    u16* Cg = (u16*)C0 + (long long)bz * c_bs;
#pragma unroll
    for (int i = 0; i < 4; ++i)
#pragma unroll
      for (int j = 0; j < 4; ++j)
#pragma unroll
        for (int r = 0; r < 4; ++r) {
          const int m = m0 + wm + i * 16 + q * 4 + r;
          const int n = n0 + wn + j * 16 + lr;
          float v = acc[i][j][r];
          v = silu_f(v * (p0[n] * 0.99999500003749969f) + p1[n]);
          Cg[(long long)m * ldc + n] = f2h(v);
        }
  } else if constexpr (EPI == EPI_RAW_F16) {
    u16* Cg = (u16*)C0 + (long long)bz * c_bs;
#pragma unroll
    for (int i = 0; i < 4; ++i)
#pragma unroll
      for (int j = 0; j < 4; ++j)
#pragma unroll
        for (int r = 0; r < 4; ++r) {
          const int m = m0 + wm + i * 16 + q * 4 + r;
          const int n = n0 + wn + j * 16 + lr;
          Cg[(long long)m * ldc + n] = f2h(acc[i][j][r]);
        }
  } else if constexpr (EPI == EPI_BNSILU_RES_M) {
    float* Cg = (float*)C0 + (long long)bz * c_bs;
    const float* rg = res + (long long)bz * res_bs;
#pragma unroll
    for (int i = 0; i < 4; ++i)
#pragma unroll
      for (int j = 0; j < 4; ++j)
#pragma unroll
        for (int r = 0; r < 4; ++r) {
          const int m = m0 + wm + i * 16 + q * 4 + r;
          const int n = n0 + wn + j * 16 + lr;
          float v = acc[i][j][r];
          v = silu_f(v * (p0[m] * 0.99999500003749969f) + p1[m]);
          const long long idx = (long long)m * ldc + n;
          Cg[idx] = v + rg[idx];
        }
  } else {
    // EPI_QKEV: n-segment 0=q 1=k 2=e 3=v(transposed)
    const int seg = n0 >> 8;
    const int nb = n0 & 255;  // 0 or 128
    if (seg < 3) {
      u16* dst; long long bs; int ld2;
      if (seg == 0) { dst = (u16*)C0; bs = 262144; ld2 = 256; }
      else { dst = (u16*)C1 + (seg == 2 ? 256 : 0); bs = 524288; ld2 = 512; }
      dst += (long long)bz * bs;
#pragma unroll
      for (int i = 0; i < 4; ++i)
#pragma unroll
        for (int j = 0; j < 4; ++j)
#pragma unroll
          for (int r = 0; r < 4; ++r) {
            const int m = m0 + wm + i * 16 + q * 4 + r;
            const int col = wn + j * 16 + lr;
            float v = acc[i][j][r] + p0[n0 + col];
            dst[(long long)m * ld2 + nb + col] = f2h(v);
          }
    } else {
      // v[c, j] = Y[j, 768+c] + bv[c]: transpose via LDS, 32-row slabs, stride 132
      u16* dst = (u16*)C2 + (long long)bz * 262144;
#pragma unroll
      for (int s = 0; s < 4; ++s) {
        const int rbase = s * 32;
        __syncthreads();
        if (wm == (rbase & 64)) {
          const int ibase = (rbase & 32) >> 4;
#pragma unroll
          for (int ii = 0; ii < 2; ++ii) {
            const int i = ibase + ii;
#pragma unroll
            for (int j = 0; j < 4; ++j)
#pragma unroll
              for (int r = 0; r < 4; ++r) {
                const int row32 = i * 16 + q * 4 + r - (rbase & 32);
                const int col = wn + j * 16 + lr;
                float v = acc[i][j][r] + p0[768 + nb + col];
                smem[row32 * 132 + col] = f2h(v);
              }
          }
        }
        __syncthreads();
#pragma unroll
        for (int p = 0; p < 2; ++p) {
          const int lin = p * 256 + t;
          const int c = lin >> 2;
          const int mc = lin & 3;
          u16 tmp[8];
#pragma unroll
          for (int r8 = 0; r8 < 8; ++r8)
            tmp[r8] = smem[(mc * 8 + r8) * 132 + c];
          *(half8*)&dst[(long long)(nb + c) * 1024 + m0 + rbase + mc * 8] =
              *(const half8*)tmp;
        }
      }
    }
  }
}

// ======================= 256^2 kernel (logits) ==============================
// BM=BN=256, BK=32 double-buffered in 64KB STATIC LDS (R10's 128KB dynamic
// LDS exceeded the per-block cap -> launch failure; this keeps the same
// counted-vmcnt mechanism within the limit).
// 8 waves (2M x 4N), per-wave 128x64 out (acc[8][4]). 4 loads/thread/tile,
// 2 tiles in flight. Per tile: vmcnt(4) [cur landed, next's 4 in flight]
// -> s_barrier -> 32 MFMA/wave -> sched_barrier+s_barrier (WAR) -> restage.
// Tail drains vmcnt(0). 64KB LDS + ~116 VGPR -> 2 blocks/CU possible
// (cross-block overlap on top of explicit pipeline).
template<bool DUAL>
__global__ __launch_bounds__(512, 2)
void gemm256_nt(const u16* __restrict__ A, long long a_bs, int lda,
                const u16* __restrict__ A2,
                const u16* __restrict__ B, long long b_bs, int ldb,
                u16* __restrict__ C0, long long c_bs, int ldc, int K)
{
  // A bufs [2][256][32] at 0/8192 | B bufs [2][256][32] at 16384/24576
  __shared__ u16 smem[32768];

  const int id = blockIdx.x;
  const int bz = (id & 7) + 8 * (id / (8 * 16));
  const int tt = (id >> 3) % 16;
  const int m0 = (tt & 3) * 256;
  const int n0 = (tt >> 2) * 256;
  const u16* Ab = A + (long long)bz * a_bs;
  const u16* Bb = B + (long long)bz * b_bs;
  const int t = threadIdx.x;
  const int lane = t & 63;
  const int w = t >> 6;           // 0..7
  const int wm = (w & 1) * 128;   // 2 waves in M
  const int wn = (w >> 1) * 64;   // 4 waves in N
  const int q = lane >> 4;
  const int lr = lane & 15;

  f32x4 acc[8][4];
#pragma unroll
  for (int i = 0; i < 8; ++i)
#pragma unroll
    for (int j = 0; j < 4; ++j)
      acc[i][j] = (f32x4){0.f, 0.f, 0.f, 0.f};

  const int lrow = lane >> 2;
  const int kch = (lane & 3) ^ ((lane >> 2) & 3) ^ ((lane >> 4) & 3);
  const int lk = kch * 8;
  // wave w stages rows 32w..32w+31 of the 256-row panels
  const u16* aR0 = Ab + (long long)(m0 + 32 * w + lrow) * lda + lk;
  const u16* aR1 = aR0 + 16LL * lda;
  const u16* bR0 = Bb + (long long)(n0 + 32 * w + lrow) * ldb + lk;
  const u16* bR1 = bR0 + 16LL * ldb;
  const u16* a2R0 = nullptr; const u16* a2R1 = nullptr;
  if constexpr (DUAL) {
    a2R0 = A2 + (long long)(m0 + 32 * w + lrow) * 256 + lk;
    a2R1 = a2R0 + 16LL * 256;
  }
  const int fpos = (q ^ (lr & 3) ^ ((lr >> 2) & 3)) * 8;

// 4 global_load_lds for the 32-K tile at kk into buffer p (0/1)
#define STAGE256(kk, p)                                                       \
  do {                                                                        \
    u16* _a = smem + (p) * 8192 + w * 1024;                                   \
    u16* _b = smem + 16384 + (p) * 8192 + w * 1024;                           \
    if (!DUAL || (kk) < 256) {                                                \
      glds16(aR0 + (kk), _a);  glds16(aR1 + (kk), _a + 512);                  \
    } else {                                                                  \
      glds16(a2R0 + ((kk) - 256), _a);  glds16(a2R1 + ((kk) - 256), _a + 512);\
    }                                                                         \
    glds16(bR0 + (kk), _b);  glds16(bR1 + (kk), _b + 512);                    \
  } while (0)

#define COMPUTE256(p)                                                         \
  do {                                                                        \
    half8 bfr[4];                                                             \
    _Pragma("unroll")                                                         \
    for (int j = 0; j < 4; ++j)                                               \
      bfr[j] = *(const half8*)&smem[16384 + (p) * 8192 + (wn + j * 16 + lr) * 32 + fpos]; \
    _Pragma("unroll")                                                         \
    for (int i = 0; i < 8; ++i) {                                             \
      const half8 af = *(const half8*)&smem[(p) * 8192 + (wm + i * 16 + lr) * 32 + fpos]; \
      _Pragma("unroll")                                                       \
      for (int j = 0; j < 4; ++j)                                             \
        acc[i][j] = __builtin_amdgcn_mfma_f32_16x16x32_f16(af, bfr[j], acc[i][j], 0, 0, 0); \
    }                                                                         \
  } while (0)

  // prologue: tiles 0 and 1 in flight (8 loads/thread)
  STAGE256(0, 0);
  STAGE256(32, 1);
  for (int k0 = 0; k0 < K; k0 += 64) {
    // ---- tile k0 from buffer 0 ----
    asm volatile("s_waitcnt vmcnt(4)" ::: "memory");   // buf0 landed
    __builtin_amdgcn_s_barrier();
    COMPUTE256(0);
    __builtin_amdgcn_sched_barrier(0);
    __builtin_amdgcn_s_barrier();                      // WAR: reads of buf0 done
    if (k0 + 64 < K) {
      STAGE256(k0 + 64, 0);
      asm volatile("s_waitcnt vmcnt(4)" ::: "memory"); // buf1 landed
    } else {
      asm volatile("s_waitcnt vmcnt(0)" ::: "memory"); // drain tail
    }
    // ---- tile k0+32 from buffer 1 ----
    __builtin_amdgcn_s_barrier();
    COMPUTE256(1);
    __builtin_amdgcn_sched_barrier(0);
    __builtin_amdgcn_s_barrier();                      // WAR: reads of buf1 done
    if (k0 + 96 < K) STAGE256(k0 + 96, 1);
  }
#undef STAGE256
#undef COMPUTE256

  u16* Cg = C0 + (long long)bz * c_bs;
#pragma unroll
  for (int i = 0; i < 8; ++i)
#pragma unroll
    for (int j = 0; j < 4; ++j)
#pragma unroll
      for (int r = 0; r < 4; ++r) {
        const int m = m0 + wm + i * 16 + q * 4 + r;
        const int n = n0 + wn + j * 16 + lr;
        Cg[(long long)m * ldc + n] = f2h(acc[i][j][r]);
      }
}

// x [B,512,1024] fp32 -> xT [B,1024,512] fp16; 64x64 tiles,
// float4 global reads (256B/16-lane segments), half8 (16B) stores.
__global__ __launch_bounds__(256)
void transpose_x(const float* __restrict__ x, u16* __restrict__ xT) {
  __shared__ float tile[64][65];
  const int b = blockIdx.z;
  const int n0 = blockIdx.x * 64;
  const int d0 = blockIdx.y * 64;
  const int t = threadIdx.x;
  const float* src = x + (long long)b * 524288;
  const int rr = t >> 4;   // 0..15
  const int cc = t & 15;   // float4 column
#pragma unroll
  for (int i = 0; i < 4; ++i) {
    const int r = rr + i * 16;
    const float4 v = *(const float4*)&src[(long long)(d0 + r) * 1024 + n0 + cc * 4];
    tile[r][cc * 4 + 0] = v.x;
    tile[r][cc * 4 + 1] = v.y;
    tile[r][cc * 4 + 2] = v.z;
    tile[r][cc * 4 + 3] = v.w;
  }
  __syncthreads();
  u16* dst = xT + (long long)b * 524288;
  const int d8 = t & 7;    // 8-wide d slot
  const int nn = t >> 3;   // 0..31
#pragma unroll
  for (int i = 0; i < 2; ++i) {
    const int n = nn + i * 32;
    u16 tmp[8];
#pragma unroll
    for (int e = 0; e < 8; ++e) tmp[e] = f2h(tile[d8 * 8 + e][n]);
    *(half8*)&dst[(long long)(n0 + n) * 512 + d0 + d8 * 8] = *(const half8*)tmp;
  }
}

// weights: w1 | stacked(wq,wk,we,wv) | w2 -> fp16; fused bias (fp32) qkev
__global__ __launch_bounds__(256)
void convert_w(const float* __restrict__ w1, const float* __restrict__ wq,
               const float* __restrict__ wk, const float* __restrict__ wv,
               const float* __restrict__ we, const float* __restrict__ w2,
               const float* __restrict__ bq, const float* __restrict__ bk,
               const float* __restrict__ be, const float* __restrict__ bv,
               u16* __restrict__ dstw, float* __restrict__ bbuf) {
  int id = blockIdx.x * 256 + threadIdx.x;
  if (id < 524288) {
    float v;
    if (id < 131072) v = w1[id];
    else if (id < 393216) {
      int s = id - 131072, o = s >> 8, c = s & 255;
      if (o < 256) v = wq[o * 256 + c];
      else if (o < 512) v = wk[(o - 256) * 256 + c];
      else if (o < 768) v = we[(o - 512) * 256 + c];
      else v = wv[(o - 768) * 256 + c];
    } else v = w2[id - 393216];
    dstw[id] = f2h(v);
  } else {
    int i = id - 524288;
    float v;
    if (i < 256) v = bq[i];
    else if (i < 512) v = bk[i - 256];
    else if (i < 768) v = be[i - 512];
    else v = bv[i - 768];
    bbuf[i] = v;
  }
}

// posT[n,c] = fp16(rel_h[c, n>>5] + rel_w[c, n&31])
__global__ __launch_bounds__(256)
void pos_compute(const float* __restrict__ rh, const float* __restrict__ rw,
                 u16* __restrict__ posT) {
  const int n = blockIdx.x;
  const int c = threadIdx.x;
  posT[n * 256 + c] = f2h(rh[c * 32 + (n >> 5)] + rw[c * 32 + (n & 31)]);
}

// in-place softmax on fp16 rows of 1024; 2 rows/block, 16B/lane
__global__ __launch_bounds__(256)
void softmax_rows(u16* __restrict__ logits) {
  __shared__ float redm[2][2], reds[2][2];
  const int t = threadIdx.x;
  const int row = t >> 7;          // 0/1
  const int l = t & 127;           // lane within row
  const int wv = (t >> 6) & 1;     // wave within row
  u16* p = logits + (long long)blockIdx.x * 2048 + row * 1024;
  half8 raw = ((const half8*)p)[l];
  float v[8];
#pragma unroll
  for (int e = 0; e < 8; ++e) v[e] = (float)raw[e];
  float mx = v[0];
#pragma unroll
  for (int e = 1; e < 8; ++e) mx = fmaxf(mx, v[e]);
#pragma unroll
  for (int off = 32; off > 0; off >>= 1) mx = fmaxf(mx, __shfl_down(mx, off));
  if ((t & 63) == 0) redm[row][wv] = mx;
  __syncthreads();
  mx = fmaxf(redm[row][0], redm[row][1]);
  float ev[8];
  float s = 0.f;
#pragma unroll
  for (int e = 0; e < 8; ++e) { ev[e] = __expf(v[e] - mx); s += ev[e]; }
#pragma unroll
  for (int off = 32; off > 0; off >>= 1) s += __shfl_down(s, off);
  if ((t & 63) == 0) reds[row][wv] = s;
  __syncthreads();
  const float inv = 1.0f / (reds[row][0] + reds[row][1]);
  half8 o;
#pragma unroll
  for (int e = 0; e < 8; ++e) o[e] = (_Float16)(ev[e] * inv);
  ((half8*)p)[l] = o;
}

extern "C" void kernel_launch(void* const* d_in, const int* in_sizes, int n_in,
                              void* d_out, int out_size, void* d_ws, size_t ws_size,
                              hipStream_t stream) {
  const float* x  = (const float*)d_in[0];
  const float* w1 = (const float*)d_in[1];
  const float* g1 = (const float*)d_in[2];
  const float* b1 = (const float*)d_in[3];
  const float* wq = (const float*)d_in[4];
  const float* bq = (const float*)d_in[5];
  const float* wk = (const float*)d_in[6];
  const float* bk = (const float*)d_in[7];
  const float* wv = (const float*)d_in[8];
  const float* bv = (const float*)d_in[9];
  const float* we = (const float*)d_in[10];
  const float* be = (const float*)d_in[11];
  const float* rh = (const float*)d_in[12];
  const float* rw = (const float*)d_in[13];
  const float* w2 = (const float*)d_in[14];
  const float* g2 = (const float*)d_in[15];
  const float* b2 = (const float*)d_in[16];
  float* out = (float*)d_out;
  char* ws = (char*)d_ws;

  // ---- workspace (256 MiB available) ----
  u16* xT     = (u16*)(ws + 0);           // [B,1024,512] f16   32 MiB
  u16* x1t    = (u16*)(ws + 33554432);    // [B,1024,256] f16   16 MiB
  u16* qbuf   = (u16*)(ws + 50331648);    // [B,1024,256] f16   16 MiB
  u16* kcat   = (u16*)(ws + 67108864);    // [B,1024,512] f16   32 MiB (k|e)
  u16* vbuf   = (u16*)(ws + 100663296);   // [B,256,1024] f16   16 MiB
  u16* outt   = (u16*)(ws + 117440512);   // [B,1024,256] f16   16 MiB
  u16* posT   = (u16*)(ws + 134217728);   // [1024,256]   f16  512 KiB
  u16* wbuf   = (u16*)(ws + 134742016);   // packed weights      1 MiB
  float* bbuf = (float*)(ws + 135790592); // fused qkev bias     4 KiB
  u16* logits = (u16*)(ws + 142606336);   // [B,1024,1024] f16  64 MiB

  u16* w1b    = wbuf;            // [256,512]
  u16* wqkve  = wbuf + 131072;   // [1024,256] stacked q|k|e|v
  u16* w2b    = wbuf + 393216;   // [512,256]

  transpose_x<<<dim3(16, 8, 32), 256, 0, stream>>>(x, xT);
  convert_w<<<dim3(2052), 256, 0, stream>>>(w1, wq, wk, wv, we, w2,
                                            bq, bk, be, bv, wbuf, bbuf);
  pos_compute<<<dim3(1024), 256, 0, stream>>>(rh, rw, posT);

  // cv1: x1t[n,c] = silu(bn(xT[n,:] . w1[c,:]))   M=1024 N=256 K=512
  gemm_nt<EPI_BNSILU_N, false, 16, 8><<<dim3(512), 256, 0, stream>>>(
      xT, 524288LL, 512, nullptr, w1b, 0LL, 512,
      x1t, 262144LL, 256, nullptr, nullptr, 512, g1, b1, nullptr, 0LL);

  // fused qkev: Y[n,o] = x1t[n,:] . wqkve[o,:] + b[o]   M=1024 N=1024 K=256
  gemm_nt<EPI_QKEV, false, 64, 8><<<dim3(2048), 256, 0, stream>>>(
      x1t, 262144LL, 256, nullptr, wqkve, 0LL, 256,
      qbuf, 262144LL, 256, kcat, vbuf, 256, bbuf, nullptr, nullptr, 0LL);

  // logits[i,j] = [q(b)|posT][i,:] . kcat[j,:]   M=1024 N=1024 K=512 (dual A)
  // 256^2 dbuf BK=32 counted-vmcnt kernel: 512 blocks x 512 thr, 64 KB static
  gemm256_nt<true><<<dim3(512), 512, 0, stream>>>(
      qbuf, 262144LL, 256, posT, kcat, 524288LL, 512,
      logits, 1048576LL, 1024, 512);

  // softmax in place over all 32K rows (2 rows per block)
  softmax_rows<<<dim3(16384), 256, 0, stream>>>(logits);

  // outt[i,c] = attn[i,:] . vbuf[c,:]   M=1024 N=256 K=1024
  gemm_nt<EPI_RAW_F16, false, 16, 8><<<dim3(512), 256, 0, stream>>>(
      logits, 1048576LL, 1024, nullptr, vbuf, 262144LL, 1024,
      outt, 262144LL, 256, nullptr, nullptr, 1024, nullptr, nullptr, nullptr, 0LL);

  // cv2 + residual: out = x + silu(bn(w2 . outt))   M=512 N=1024 K=256
  gemm_nt<EPI_BNSILU_RES_M, false, 32, 4><<<dim3(1024), 256, 0, stream>>>(
      w2b, 0LL, 256, nullptr, outt, 262144LL, 256,
      out, 524288LL, 1024, nullptr, nullptr, 256, g2, b2, x, 524288LL);
}